// Round 10
// baseline (109.591 us; speedup 1.0000x reference)
//
#include <hip/hip_runtime.h>
#include <cmath>
#include <complex>
#include <cstring>
#include <algorithm>

#define DIM_IN  288
#define DIM_SHD 9
#define NB      10
#define NH      16
#define EPB     32
#define BLOCK   256
#define NINSTR  11
#define XSTR    292
#define ZSTR    164
#define W2B_ELEMS (NINSTR * 32 * 32 * 32)   // [ins][u][w][t0..31]; t=16 holds b2, t>16 zero

// LDS pool (floats), total 20224 fl = 80896 B -> 2 blocks/CU (161792 <= 163840):
//   s_xo : [0, 9344)          32*292, x staging; reused for out gather
//   s_z0 : [9344, 14592)      32*164
//   s_z1 : [14592, 19840)     32*164
//   s_sh : [19840, 20224)     32*12
//   s_hb : alias s_z1 (1024 ushort; dead after hB hoist, barrier-protected)
#define OFF_XO 0
#define OFF_Z  9344
#define OFF_SH 19840
#define POOLSZ 20224

typedef __attribute__((ext_vector_type(8))) short  short8b;
typedef __attribute__((ext_vector_type(4))) float  f32x4;

__device__ float g_C[NINSTR][125];

__device__ __forceinline__ unsigned short f2bf(float f) {
  unsigned int u = __float_as_uint(f);
  unsigned int r = (u + 0x7fffu + ((u >> 16) & 1u)) >> 16;   // RNE
  return (unsigned short)r;
}

// W2 -> bf16 [ins][u][w][t]; t<16 = W2 row t, t==16 = b2 (hB carries 1.0 there), t>16 = 0
__global__ __launch_bounds__(256) void prep_w2(const float* __restrict__ W2,
                                               const float* __restrict__ b2,
                                               unsigned short* __restrict__ W2b) {
  int gid = blockIdx.x * 256 + threadIdx.x;
  if (gid < W2B_ELEMS) {
    int c = gid >> 5, t = gid & 31;          // c = ins*1024 + u*32 + w
    float v = (t < 16) ? W2[(size_t)t * 11264 + c] : (t == 16 ? b2[c] : 0.0f);
    W2b[gid] = f2bf(v);
  }
}

// ---- z-phase: 32 edges x 32 u over 256 threads, LDS->LDS (shared, barriered) ----
template<int INS,int D1,int D2,int D3,int OFF1,int OFF2>
__device__ __forceinline__ void z_phase(
    int tid, const float* __restrict__ s_x,
    const float* __restrict__ s_sh, float* __restrict__ zdst)
{
  const float* __restrict__ Cp = g_C[INS];
  #pragma unroll
  for (int s = 0; s < 4; ++s) {
    int id = tid + s * BLOCK;
    int e = id >> 5, u = id & 31;
    const float* xe = s_x + e * XSTR + OFF1 + u * D1;
    float zk[D3];
    #pragma unroll
    for (int k = 0; k < D3; ++k) zk[k] = 0.f;
    #pragma unroll
    for (int i = 0; i < D1; ++i) {
      float xv = xe[i];
      #pragma unroll
      for (int j = 0; j < D2; ++j) {
        float pr = xv * s_sh[e * 12 + OFF2 + j];
        #pragma unroll
        for (int k = 0; k < D3; ++k)
          zk[k] = fmaf(Cp[(i * D2 + j) * D3 + k], pr, zk[k]);
      }
    }
    #pragma unroll
    for (int k = 0; k < D3; ++k) zdst[e * ZSTR + k * 32 + u] = zk[k];   // 2-way, free
  }
}

// ---- MFMA weight-gen (bias folded) + u-contraction; A shared by 2 e-tiles ----
template<int INS,int D3,int SB>
__device__ __forceinline__ void contract2(
    int ls, int lq, int a_wt, int b_uh,
    const unsigned short* __restrict__ W2b,
    const float* __restrict__ zbuf, short8b hB0, short8b hB1,
    float (&acc)[2][4][9])
{
  const unsigned short* Ap =
      W2b + ((size_t)(INS * 32 + b_uh * 16) * 32 + a_wt * 16 + ls) * 32 + lq * 8;
  const float* zb0 = zbuf + ls * ZSTR + b_uh * 16;
  const float* zb1 = zbuf + (16 + ls) * ZSTR + b_uh * 16;
  const f32x4 zero4 = {0.f, 0.f, 0.f, 0.f};

  short8b Ra = *(const short8b*)(Ap);
  f32x4 w0_cur = __builtin_amdgcn_mfma_f32_16x16x32_bf16(Ra, hB0, zero4, 0, 0, 0);
  f32x4 w1_cur = __builtin_amdgcn_mfma_f32_16x16x32_bf16(Ra, hB1, zero4, 0, 0, 0);
  short8b Rb = *(const short8b*)(Ap + 1024);

  #pragma unroll
  for (int c = 0; c < 4; ++c) {
    float4 zq0[D3], zq1[D3];
    #pragma unroll
    for (int k = 0; k < D3; ++k) {
      zq0[k] = *(const float4*)(zb0 + k * 32 + c * 4);   // 2-way/broadcast, free
      zq1[k] = *(const float4*)(zb1 + k * 32 + c * 4);
    }
    #pragma unroll
    for (int i = 0; i < 4; ++i) {
      const int g = c * 4 + i;              // local u index (0..15)
      f32x4 w0_next, w1_next;
      if (g < 15) {
        w0_next = __builtin_amdgcn_mfma_f32_16x16x32_bf16(Rb, hB0, zero4, 0, 0, 0);
        w1_next = __builtin_amdgcn_mfma_f32_16x16x32_bf16(Rb, hB1, zero4, 0, 0, 0);
        if (g + 2 < 16) Rb = *(const short8b*)(Ap + (size_t)(g + 2) * 1024);
      }
      #pragma unroll
      for (int k = 0; k < D3; ++k) {
        const float z0 = (i == 0) ? zq0[k].x : (i == 1) ? zq0[k].y
                       : (i == 2) ? zq0[k].z : zq0[k].w;
        const float z1 = (i == 0) ? zq1[k].x : (i == 1) ? zq1[k].y
                       : (i == 2) ? zq1[k].z : zq1[k].w;
        acc[0][0][SB + k] = fmaf(w0_cur[0], z0, acc[0][0][SB + k]);
        acc[0][1][SB + k] = fmaf(w0_cur[1], z0, acc[0][1][SB + k]);
        acc[0][2][SB + k] = fmaf(w0_cur[2], z0, acc[0][2][SB + k]);
        acc[0][3][SB + k] = fmaf(w0_cur[3], z0, acc[0][3][SB + k]);
        acc[1][0][SB + k] = fmaf(w1_cur[0], z1, acc[1][0][SB + k]);
        acc[1][1][SB + k] = fmaf(w1_cur[1], z1, acc[1][1][SB + k]);
        acc[1][2][SB + k] = fmaf(w1_cur[2], z1, acc[1][2][SB + k]);
        acc[1][3][SB + k] = fmaf(w1_cur[3], z1, acc[1][3][SB + k]);
      }
      if (g < 15) { w0_cur = w0_next; w1_cur = w1_next; }
    }
  }
}

// NOTE (journal): VGPR cap = 256 / (2nd launch_bounds arg) on this hipcc:
// arg=2 -> 128 (r4/r5/r7/r8), arg=4 -> 64 (r3/r6, catastrophic spill).
// This round needs acc[2][4][9]=72 f32 -> use arg=1 (cap 256, 2 waves/SIMD).
__global__ __launch_bounds__(BLOCK, 1) void conv_kernel(
    const float* __restrict__ xg, const float* __restrict__ shg,
    const float* __restrict__ dist, const float* __restrict__ freq,
    const float* __restrict__ W1, const float* __restrict__ b1,
    const unsigned short* __restrict__ W2b,
    float* __restrict__ out)
{
  __shared__ float s_pool[POOLSZ];        // 80896 B -> 2 blocks/CU
  float* s_xo = s_pool + OFF_XO;
  float* s_z0 = s_pool + OFF_Z;
  float* s_z1 = s_pool + OFF_Z + EPB * ZSTR;
  float* s_sh = s_pool + OFF_SH;
  unsigned short* s_hb = (unsigned short*)s_z1;   // 1024 ushort, aliased

  const int tid = threadIdx.x;
  const int e0 = blockIdx.x * EPB;
  const int lane = tid & 63;
  const int ls = lane & 15;       // e-col within tile & w-row selector
  const int lq = lane >> 4;       // 0..3 k-slice / output reg quad
  const int wid = tid >> 6;       // 0..3
  const int a_wt = wid >> 1;      // w-tile 0/1
  const int b_uh = wid & 1;       // u-half 0/1

  // ---- prologue 1: stage x (coalesced) + sh ----
  for (int i4 = tid; i4 < EPB * 72; i4 += BLOCK) {
    int e = i4 / 72, r = i4 - e * 72;
    *(float4*)(s_xo + e * XSTR + r * 4) =
        *(const float4*)(xg + (size_t)(e0 + e) * DIM_IN + r * 4);
  }
  for (int i = tid; i < EPB * DIM_SHD; i += BLOCK) {
    int e = i / DIM_SHD, c = i - (i / DIM_SHD) * DIM_SHD;
    s_sh[e * 12 + c] = shg[(size_t)(e0 + e) * DIM_SHD + c];
  }
  __syncthreads();

  // ---- prologue 2: radial MLP (basis inline), h -> s_hb (aliased into z1) ----
  for (int i = tid; i < EPB * NH; i += BLOCK) {
    int e = i >> 4, t = i & 15;
    float d  = dist[e0 + e];
    float xv = d * 0.25f;
    float x2 = xv * xv, x4 = x2 * x2, x5 = x4 * xv;
    float env = 1.0f / xv + x5 * fmaf(xv, fmaf(xv, -21.0f, 48.0f), -28.0f);
    env = (xv < 1.0f) ? env : 0.0f;
    float v = b1[t];
    #pragma unroll
    for (int n = 0; n < NB; ++n)
      v = fmaf(env * sinf(freq[n] * xv), W1[n * NH + t], v);
    v = v / (1.0f + expf(-v));          // silu
    s_hb[e * 32 + t] = f2bf(v);
    s_hb[e * 32 + t + 16] = (t == 0) ? (unsigned short)0x3F80 : (unsigned short)0;
  }
  z_phase< 0, 1, 1, 1,   0, 0>(tid, s_xo, s_sh, s_z0);
  __syncthreads();
  short8b hB0 = *(const short8b*)(s_hb + ls * 32 + lq * 8);
  short8b hB1 = *(const short8b*)(s_hb + (16 + ls) * 32 + lq * 8);
  __syncthreads();   // all waves hold hB before z_phase<1> overwrites s_hb (z1)

  float acc[2][4][9];
  #pragma unroll
  for (int et = 0; et < 2; ++et)
    #pragma unroll
    for (int r = 0; r < 4; ++r)
      #pragma unroll
      for (int a = 0; a < 9; ++a) acc[et][r][a] = 0.f;

  // ---- pipelined main: z(i+1) || contract(i), one barrier each ----
  z_phase< 1, 1, 3, 3,   0, 1>(tid, s_xo, s_sh, s_z1);
  contract2< 0, 1, 0>(ls, lq, a_wt, b_uh, W2b, s_z0, hB0, hB1, acc);
  __syncthreads();
  z_phase< 2, 1, 5, 5,   0, 4>(tid, s_xo, s_sh, s_z0);
  contract2< 1, 3, 1>(ls, lq, a_wt, b_uh, W2b, s_z1, hB0, hB1, acc);
  __syncthreads();
  z_phase< 3, 3, 1, 3,  32, 0>(tid, s_xo, s_sh, s_z1);
  contract2< 2, 5, 4>(ls, lq, a_wt, b_uh, W2b, s_z0, hB0, hB1, acc);
  __syncthreads();
  z_phase< 4, 3, 3, 1,  32, 1>(tid, s_xo, s_sh, s_z0);
  contract2< 3, 3, 1>(ls, lq, a_wt, b_uh, W2b, s_z1, hB0, hB1, acc);
  __syncthreads();
  z_phase< 5, 3, 3, 5,  32, 1>(tid, s_xo, s_sh, s_z1);
  contract2< 4, 1, 0>(ls, lq, a_wt, b_uh, W2b, s_z0, hB0, hB1, acc);
  __syncthreads();
  z_phase< 6, 3, 5, 3,  32, 4>(tid, s_xo, s_sh, s_z0);
  contract2< 5, 5, 4>(ls, lq, a_wt, b_uh, W2b, s_z1, hB0, hB1, acc);
  __syncthreads();
  z_phase< 7, 5, 1, 5, 128, 0>(tid, s_xo, s_sh, s_z1);
  contract2< 6, 3, 1>(ls, lq, a_wt, b_uh, W2b, s_z0, hB0, hB1, acc);
  __syncthreads();
  z_phase< 8, 5, 3, 3, 128, 1>(tid, s_xo, s_sh, s_z0);
  contract2< 7, 5, 4>(ls, lq, a_wt, b_uh, W2b, s_z1, hB0, hB1, acc);
  __syncthreads();
  z_phase< 9, 5, 5, 1, 128, 4>(tid, s_xo, s_sh, s_z1);
  contract2< 8, 3, 1>(ls, lq, a_wt, b_uh, W2b, s_z0, hB0, hB1, acc);
  __syncthreads();
  z_phase<10, 5, 5, 5, 128, 4>(tid, s_xo, s_sh, s_z0);
  contract2< 9, 1, 0>(ls, lq, a_wt, b_uh, W2b, s_z1, hB0, hB1, acc);
  __syncthreads();
  contract2<10, 5, 4>(ls, lq, a_wt, b_uh, W2b, s_z0, hB0, hB1, acc);

  // ---- epilogue: cross-wave u-half reduction into s_xo, coalesced store ----
  __syncthreads();   // everyone done reading s_xo (x) / s_z before overwrite
  if (b_uh == 1) {
    #pragma unroll
    for (int et = 0; et < 2; ++et) {
      float* row = s_xo + (et * 16 + ls) * XSTR;
      #pragma unroll
      for (int r = 0; r < 4; ++r) {
        int w = a_wt * 16 + lq * 4 + r;
        row[w] = acc[et][r][0];
        #pragma unroll
        for (int k = 0; k < 3; ++k) row[32 + w * 3 + k] = acc[et][r][1 + k];
        #pragma unroll
        for (int k = 0; k < 5; ++k) row[128 + w * 5 + k] = acc[et][r][4 + k];
      }
    }
  }
  __syncthreads();
  if (b_uh == 0) {
    #pragma unroll
    for (int et = 0; et < 2; ++et) {
      float* row = s_xo + (et * 16 + ls) * XSTR;
      #pragma unroll
      for (int r = 0; r < 4; ++r) {
        int w = a_wt * 16 + lq * 4 + r;
        row[w] += acc[et][r][0];
        #pragma unroll
        for (int k = 0; k < 3; ++k) row[32 + w * 3 + k] += acc[et][r][1 + k];
        #pragma unroll
        for (int k = 0; k < 5; ++k) row[128 + w * 5 + k] += acc[et][r][4 + k];
      }
    }
  }
  __syncthreads();
  for (int i4 = tid; i4 < EPB * 72; i4 += BLOCK) {
    int e = i4 / 72, r = i4 - e * 72;
    float4 v = *(const float4*)(s_xo + e * XSTR + r * 4);
    *(float4*)(out + (size_t)(e0 + e) * DIM_IN + r * 4) = v;
  }
}

// ===================== host-side Wigner-3j (mirrors reference) =====================
typedef std::complex<double> cd;

static double factd(int n) { double r = 1; for (int i = 2; i <= n; ++i) r *= i; return r; }

static double su2_cg(int j1, int j2, int j3, int m1, int m2, int m3) {
  if (m3 != m1 + m2) return 0.0;
  int vmin = std::max(std::max(-j1 + j2 + m3, -j1 + m1), 0);
  int vmax = std::min(std::min(j2 + j3 + m1, j3 - j1 + j2), j3 + m3);
  if (vmax < vmin) return 0.0;
  double c = std::sqrt(
      factd(2*j3+1) * factd(j3+j1-j2) * factd(j3-j1+j2) * factd(j1+j2-j3) / factd(j1+j2+j3+1)
      * factd(j3+m3) * factd(j3-m3)
      / (factd(j1+m1) * factd(j1-m1) * factd(j2+m2) * factd(j2-m2)));
  double s = 0.0;
  for (int v = vmin; v <= vmax; ++v) {
    double sg = ((v + j2 + m2) & 1) ? -1.0 : 1.0;
    s += sg * factd(j2+j3+m1-v) * factd(j1-m1+v)
         / (factd(v) * factd(j3-j1+j2-v) * factd(j3+m3-v) * factd(v+j1-j2-m3));
  }
  return c * s;
}

static void qmat(int l, cd q[5][5]) {
  for (int a = 0; a < 5; ++a) for (int b = 0; b < 5; ++b) q[a][b] = cd(0, 0);
  const double s = 1.0 / std::sqrt(2.0);
  for (int m = -l; m < 0; ++m) {
    q[l + m][l - m] = cd(s, 0);
    q[l + m][l + m] = cd(0, -s);
  }
  q[l][l] = cd(1, 0);
  for (int m = 1; m <= l; ++m) {
    double sg = (m & 1) ? -1.0 : 1.0;
    q[l + m][l + m] = cd(sg * s, 0);
    q[l + m][l - m] = cd(0, sg * s);
  }
  cd ph = (l == 0) ? cd(1, 0) : (l == 1) ? cd(0, -1) : cd(-1, 0);  // (-i)^l
  for (int a = 0; a < 5; ++a) for (int b = 0; b < 5; ++b) q[a][b] *= ph;
}

static void wigner3j(int l1, int l2, int l3, double C[5][5][5]) {
  int d1 = 2*l1+1, d2 = 2*l2+1, d3 = 2*l3+1;
  cd q1[5][5], q2[5][5], q3[5][5];
  qmat(l1, q1); qmat(l2, q2); qmat(l3, q3);
  double norm2 = 0;
  for (int j = 0; j < d1; ++j)
    for (int l = 0; l < d2; ++l)
      for (int n = 0; n < d3; ++n) {
        cd sum(0, 0);
        for (int i = 0; i < d1; ++i)
          for (int k = 0; k < d2; ++k)
            for (int m = 0; m < d3; ++m) {
              double cg = su2_cg(l1, l2, l3, i - l1, k - l2, m - l3);
              if (cg != 0.0) sum += q1[i][j] * q2[k][l] * std::conj(q3[m][n]) * cg;
            }
        C[j][l][n] = sum.real();
        norm2 += C[j][l][n] * C[j][l][n];
      }
  double nrm = std::sqrt(norm2);
  if (nrm > 0)
    for (int j = 0; j < d1; ++j)
      for (int l = 0; l < d2; ++l)
        for (int n = 0; n < d3; ++n) C[j][l][n] /= nrm;
}

static void build_C_host(float C_out[NINSTR][125]) {
  const int L1[NINSTR] = {0,0,0,1,1,1,1,2,2,2,2};
  const int L2[NINSTR] = {0,1,2,0,1,1,2,0,1,2,2};
  const int L3[NINSTR] = {0,1,2,1,0,2,1,2,1,0,2};
  std::memset(C_out, 0, sizeof(float) * NINSTR * 125);
  for (int ins = 0; ins < NINSTR; ++ins) {
    int l1 = L1[ins], l2 = L2[ins], l3 = L3[ins];
    int d1 = 2*l1+1, d2 = 2*l2+1, d3 = 2*l3+1;
    double C[5][5][5];
    wigner3j(l1, l2, l3, C);
    double fan = (l3 == 0) ? 96.0 : 128.0;
    double pw = std::sqrt((2*l3+1) / fan);
    for (int i = 0; i < d1; ++i)
      for (int j = 0; j < d2; ++j)
        for (int k = 0; k < d3; ++k)
          C_out[ins][(i * d2 + j) * d3 + k] = (float)(pw * C[i][j][k]);
  }
}

extern "C" void kernel_launch(void* const* d_in, const int* in_sizes, int n_in,
                              void* d_out, int out_size, void* d_ws, size_t ws_size,
                              hipStream_t stream) {
  static float hC[NINSTR][125];
  build_C_host(hC);
  void* dC = nullptr;
  hipGetSymbolAddress(&dC, HIP_SYMBOL(g_C));
  hipMemcpyAsync(dC, hC, sizeof(hC), hipMemcpyHostToDevice, stream);

  const float* xg   = (const float*)d_in[0];
  const float* shg  = (const float*)d_in[1];
  const float* dist = (const float*)d_in[2];
  const float* freq = (const float*)d_in[3];
  const float* W1   = (const float*)d_in[4];
  const float* b1   = (const float*)d_in[5];
  const float* W2   = (const float*)d_in[6];
  const float* b2   = (const float*)d_in[7];
  float* out = (float*)d_out;
  unsigned short* W2b = (unsigned short*)d_ws;    // 720896 bytes

  prep_w2<<<(W2B_ELEMS + 255) / 256, 256, 0, stream>>>(W2, b2, W2b);

  int E = in_sizes[2];            // 16384
  int blocks = E / EPB;           // 512
  conv_kernel<<<blocks, BLOCK, 0, stream>>>(xg, shg, dist, freq, W1, b1, W2b, out);
}

// Round 11
// 71.716 us; speedup vs baseline: 1.5281x; 1.5281x over previous
//
#include <hip/hip_runtime.h>
#include <cmath>
#include <complex>
#include <cstring>
#include <algorithm>

#define DIM_IN  288
#define DIM_SHD 9
#define NB      10
#define NH      16
#define EPB     16
#define BLOCK   256
#define NINSTR  11
#define XSTR    292
#define ZSTR    164
#define W2B_ELEMS (NINSTR * 32 * 32 * 32)   // [ins][u][w][t0..31]; t=16 holds b2, t>16 zero

// LDS pool layout (floats), total 10112 fl = 40448 B -> 4 blocks/CU:
//   s_xo : [0, 4672)         16*292  x staging; reused for out gather
//   s_z  : [4672, 9920)      2*16*164 z double buffer
//   s_sh : [9920, 10112)     16*12
//   s_basis: alias s_z[1][0..160)             (dead before z_phase<1>)
//   s_hb   : alias s_z[1][160..288) as ushort (dead before z_phase<1>)
#define OFF_XO 0
#define OFF_Z  4672
#define OFF_SH 9920
#define POOLSZ 10112

typedef __attribute__((ext_vector_type(8))) short  short8b;
typedef __attribute__((ext_vector_type(4))) float  f32x4;
typedef __attribute__((ext_vector_type(2))) float  f32x2;

__device__ float g_C[NINSTR][125];

__device__ __forceinline__ unsigned short f2bf(float f) {
  unsigned int u = __float_as_uint(f);
  unsigned int r = (u + 0x7fffu + ((u >> 16) & 1u)) >> 16;   // RNE
  return (unsigned short)r;
}

// W2 -> bf16 [ins][u][w][t]; t<16 = W2 row t, t==16 = b2 (hB carries 1.0 there), t>16 = 0
__global__ __launch_bounds__(256) void prep_w2(const float* __restrict__ W2,
                                               const float* __restrict__ b2,
                                               unsigned short* __restrict__ W2b) {
  int gid = blockIdx.x * 256 + threadIdx.x;
  if (gid < W2B_ELEMS) {
    int c = gid >> 5, t = gid & 31;          // c = ins*1024 + u*32 + w
    float v = (t < 16) ? W2[(size_t)t * 11264 + c] : (t == 16 ? b2[c] : 0.0f);
    W2b[gid] = f2bf(v);
  }
}

// ---- z-phase: 16 edges x 32 u over 256 threads, LDS->LDS, pk-fma packed ----
template<int INS,int D1,int D2,int D3,int OFF1,int OFF2>
__device__ __forceinline__ void z_phase(
    int tid, const float* __restrict__ s_x,
    const float* __restrict__ s_sh, float* __restrict__ zdst)
{
  const float* __restrict__ Cp = g_C[INS];
  constexpr int NP = D3 / 2;              // D3 is odd: 1,3,5 -> 0,1,2 pairs
  #pragma unroll
  for (int s = 0; s < 2; ++s) {
    int id = tid + s * BLOCK;
    int e = id >> 5, u = id & 31;
    const float* xe = s_x + e * XSTR + OFF1 + u * D1;
    f32x2 zk2[NP > 0 ? NP : 1];
    float zkl = 0.f;
    #pragma unroll
    for (int m = 0; m < NP; ++m) zk2[m] = (f32x2){0.f, 0.f};
    #pragma unroll
    for (int i = 0; i < D1; ++i) {
      float xv = xe[i];
      #pragma unroll
      for (int j = 0; j < D2; ++j) {
        float pr = xv * s_sh[e * 12 + OFF2 + j];
        f32x2 pr2 = {pr, pr};
        const float* cb = Cp + (i * D2 + j) * D3;
        #pragma unroll
        for (int m = 0; m < NP; ++m) {
          f32x2 cc = {cb[2 * m], cb[2 * m + 1]};
          zk2[m] = __builtin_elementwise_fma(cc, pr2, zk2[m]);
        }
        zkl = fmaf(cb[D3 - 1], pr, zkl);
      }
    }
    float* zo = zdst + e * ZSTR + u;
    #pragma unroll
    for (int m = 0; m < NP; ++m) {
      zo[(2 * m) * 32]     = zk2[m].x;
      zo[(2 * m + 1) * 32] = zk2[m].y;
    }
    zo[(D3 - 1) * 32] = zkl;
  }
}

// ---- MFMA weight-gen (bias folded via t=16) + pk-fma u-contraction ----
template<int INS,int D3,int SB>
__device__ __forceinline__ void contract(
    int ls, int lq, int a_wt, int b_uh, int my_e,
    const unsigned short* __restrict__ W2b,
    const float* __restrict__ zbuf, short8b hB, f32x2 (&acc)[2][9])
{
  const unsigned short* Ap =
      W2b + ((size_t)(INS * 32 + b_uh * 16) * 32 + a_wt * 16 + ls) * 32 + lq * 8;
  const float* zb = zbuf + my_e * ZSTR + b_uh * 16;
  const f32x4 zero4 = {0.f, 0.f, 0.f, 0.f};

  short8b Ra = *(const short8b*)(Ap);
  f32x4 w_cur = __builtin_amdgcn_mfma_f32_16x16x32_bf16(Ra, hB, zero4, 0, 0, 0);
  short8b Rb = *(const short8b*)(Ap + 1024);

  #pragma unroll
  for (int c = 0; c < 4; ++c) {
    float4 zq[D3];
    #pragma unroll
    for (int k = 0; k < D3; ++k)
      zq[k] = *(const float4*)(zb + k * 32 + c * 4);
    #pragma unroll
    for (int i = 0; i < 4; ++i) {
      const int g = c * 4 + i;              // local u index (0..15)
      f32x4 w_next;
      if (g < 15) {
        w_next = __builtin_amdgcn_mfma_f32_16x16x32_bf16(Rb, hB, zero4, 0, 0, 0);
        if (g + 2 < 16) Rb = *(const short8b*)(Ap + (size_t)(g + 2) * 1024);
      }
      f32x2 wlo = {w_cur[0], w_cur[1]};     // MFMA dst pair-aligned: free extract
      f32x2 whi = {w_cur[2], w_cur[3]};
      #pragma unroll
      for (int k = 0; k < D3; ++k) {
        const float zz = (i == 0) ? zq[k].x : (i == 1) ? zq[k].y
                       : (i == 2) ? zq[k].z : zq[k].w;
        f32x2 zv = {zz, zz};
        acc[0][SB + k] = __builtin_elementwise_fma(wlo, zv, acc[0][SB + k]);
        acc[1][SB + k] = __builtin_elementwise_fma(whi, zv, acc[1][SB + k]);
      }
      if (g < 15) w_cur = w_next;
    }
  }
}

// NOTE (journal): VGPR cap = 256 / (2nd launch_bounds arg) on this hipcc:
// arg=2 -> 128 (r4/r5/r7/r8), arg=4 -> 64 (r3/r6, catastrophic spill),
// arg=1 -> 256 (r10: VGPR 252, occupancy 11%, REGRESSED — TLP > ILP here).
__global__ __launch_bounds__(BLOCK, 2) void conv_kernel(
    const float* __restrict__ xg, const float* __restrict__ shg,
    const float* __restrict__ dist, const float* __restrict__ freq,
    const float* __restrict__ W1, const float* __restrict__ b1,
    const unsigned short* __restrict__ W2b,
    float* __restrict__ out)
{
  __shared__ float s_pool[POOLSZ];        // 40448 B -> 4 blocks/CU
  float* s_xo = s_pool + OFF_XO;
  float* s_z0 = s_pool + OFF_Z;
  float* s_z1 = s_pool + OFF_Z + EPB * ZSTR;
  float* s_sh = s_pool + OFF_SH;
  float* s_basis = s_z1;                                // 160 fl, aliased
  unsigned short* s_hb = (unsigned short*)(s_z1 + 160); // 512 ushort, aliased

  const int tid = threadIdx.x;
  const int e0 = blockIdx.x * EPB;
  const int l  = tid & 63;
  const int ls = l & 15;          // e-col (B/C cols) & w-row selector (A rows)
  const int lq = l >> 4;          // 0..3 k-slice / output reg quad
  const int wid = tid >> 6;       // 0..3
  const int a_wt = wid >> 1;      // w-tile 0/1
  const int b_uh = wid & 1;       // u-half 0/1
  const int my_e = ls;

  // ---- region A: stage x (coalesced), sh, radial basis ----
  for (int i4 = tid; i4 < EPB * 72; i4 += BLOCK) {
    int e = i4 / 72, r = i4 - e * 72;
    *(float4*)(s_xo + e * XSTR + r * 4) =
        *(const float4*)(xg + (size_t)(e0 + e) * DIM_IN + r * 4);
  }
  if (tid < EPB * DIM_SHD) {
    int e = tid / DIM_SHD, c = tid - (tid / DIM_SHD) * DIM_SHD;
    s_sh[e * 12 + c] = shg[(size_t)(e0 + e) * DIM_SHD + c];
  }
  if (tid < EPB * NB) {
    int e = tid / NB, n = tid - (tid / NB) * NB;
    float d  = dist[e0 + e];
    float xv = d * 0.25f;
    float x2 = xv * xv, x4 = x2 * x2, x5 = x4 * xv;
    float env = 1.0f / xv + x5 * fmaf(xv, fmaf(xv, -21.0f, 48.0f), -28.0f);
    env = (xv < 1.0f) ? env : 0.0f;
    s_basis[e * NB + n] = env * sinf(freq[n] * xv);
  }
  __syncthreads();

  // ---- region B: radial MLP hidden layer (256 tasks) + z for instr 0 ----
  {
    int e = tid >> 4, t = tid & 15;
    float v = b1[t];
    #pragma unroll
    for (int n = 0; n < NB; ++n) v = fmaf(s_basis[e * NB + n], W1[n * NH + t], v);
    v = v / (1.0f + expf(-v));          // silu
    s_hb[e * 32 + t] = f2bf(v);
    s_hb[e * 32 + t + 16] = (t == 0) ? (unsigned short)0x3F80 : (unsigned short)0;
  }
  z_phase< 0, 1, 1, 1,   0, 0>(tid, s_xo, s_sh, s_z0);
  __syncthreads();

  short8b hB = *(const short8b*)(s_hb + my_e * 32 + lq * 8);
  __syncthreads();   // protect aliased s_basis/s_hb before z_phase<1> overwrite

  f32x2 acc[2][9];
  #pragma unroll
  for (int p = 0; p < 2; ++p)
    #pragma unroll
    for (int a = 0; a < 9; ++a) acc[p][a] = (f32x2){0.f, 0.f};

  // ---- pipelined main: z(i+1) || contract(i), one barrier each ----
  z_phase< 1, 1, 3, 3,   0, 1>(tid, s_xo, s_sh, s_z1);
  contract< 0, 1, 0>(ls, lq, a_wt, b_uh, my_e, W2b, s_z0, hB, acc);
  __syncthreads();
  z_phase< 2, 1, 5, 5,   0, 4>(tid, s_xo, s_sh, s_z0);
  contract< 1, 3, 1>(ls, lq, a_wt, b_uh, my_e, W2b, s_z1, hB, acc);
  __syncthreads();
  z_phase< 3, 3, 1, 3,  32, 0>(tid, s_xo, s_sh, s_z1);
  contract< 2, 5, 4>(ls, lq, a_wt, b_uh, my_e, W2b, s_z0, hB, acc);
  __syncthreads();
  z_phase< 4, 3, 3, 1,  32, 1>(tid, s_xo, s_sh, s_z0);
  contract< 3, 3, 1>(ls, lq, a_wt, b_uh, my_e, W2b, s_z1, hB, acc);
  __syncthreads();
  z_phase< 5, 3, 3, 5,  32, 1>(tid, s_xo, s_sh, s_z1);
  contract< 4, 1, 0>(ls, lq, a_wt, b_uh, my_e, W2b, s_z0, hB, acc);
  __syncthreads();
  z_phase< 6, 3, 5, 3,  32, 4>(tid, s_xo, s_sh, s_z0);
  contract< 5, 5, 4>(ls, lq, a_wt, b_uh, my_e, W2b, s_z1, hB, acc);
  __syncthreads();
  z_phase< 7, 5, 1, 5, 128, 0>(tid, s_xo, s_sh, s_z1);
  contract< 6, 3, 1>(ls, lq, a_wt, b_uh, my_e, W2b, s_z0, hB, acc);
  __syncthreads();
  z_phase< 8, 5, 3, 3, 128, 1>(tid, s_xo, s_sh, s_z0);
  contract< 7, 5, 4>(ls, lq, a_wt, b_uh, my_e, W2b, s_z1, hB, acc);
  __syncthreads();
  z_phase< 9, 5, 5, 1, 128, 4>(tid, s_xo, s_sh, s_z1);
  contract< 8, 3, 1>(ls, lq, a_wt, b_uh, my_e, W2b, s_z0, hB, acc);
  __syncthreads();
  z_phase<10, 5, 5, 5, 128, 4>(tid, s_xo, s_sh, s_z0);
  contract< 9, 1, 0>(ls, lq, a_wt, b_uh, my_e, W2b, s_z1, hB, acc);
  __syncthreads();
  contract<10, 5, 4>(ls, lq, a_wt, b_uh, my_e, W2b, s_z0, hB, acc);

  // ---- unpack acc pairs ----
  float accu[4][9];
  #pragma unroll
  for (int a = 0; a < 9; ++a) {
    accu[0][a] = acc[0][a].x;
    accu[1][a] = acc[0][a].y;
    accu[2][a] = acc[1][a].x;
    accu[3][a] = acc[1][a].y;
  }

  // ---- cross-wave (u-half) reduction into s_xo (x reads all done) ----
  __syncthreads();
  if (b_uh == 1) {
    float* row = s_xo + my_e * XSTR;
    #pragma unroll
    for (int r = 0; r < 4; ++r) {
      int w = a_wt * 16 + lq * 4 + r;
      row[w] = accu[r][0];
      #pragma unroll
      for (int k = 0; k < 3; ++k) row[32 + w * 3 + k] = accu[r][1 + k];
      #pragma unroll
      for (int k = 0; k < 5; ++k) row[128 + w * 5 + k] = accu[r][4 + k];
    }
  }
  __syncthreads();
  if (b_uh == 0) {
    float* row = s_xo + my_e * XSTR;
    #pragma unroll
    for (int r = 0; r < 4; ++r) {
      int w = a_wt * 16 + lq * 4 + r;
      row[w] += accu[r][0];
      #pragma unroll
      for (int k = 0; k < 3; ++k) row[32 + w * 3 + k] += accu[r][1 + k];
      #pragma unroll
      for (int k = 0; k < 5; ++k) row[128 + w * 5 + k] += accu[r][4 + k];
    }
  }
  __syncthreads();
  // coalesced store: 16 rows x 288 = 1152 float4
  for (int i4 = tid; i4 < EPB * 72; i4 += BLOCK) {
    int e = i4 / 72, r = i4 - e * 72;
    float4 v = *(const float4*)(s_xo + e * XSTR + r * 4);
    *(float4*)(out + (size_t)(e0 + e) * DIM_IN + r * 4) = v;
  }
}

// ===================== host-side Wigner-3j (mirrors reference) =====================
typedef std::complex<double> cd;

static double factd(int n) { double r = 1; for (int i = 2; i <= n; ++i) r *= i; return r; }

static double su2_cg(int j1, int j2, int j3, int m1, int m2, int m3) {
  if (m3 != m1 + m2) return 0.0;
  int vmin = std::max(std::max(-j1 + j2 + m3, -j1 + m1), 0);
  int vmax = std::min(std::min(j2 + j3 + m1, j3 - j1 + j2), j3 + m3);
  if (vmax < vmin) return 0.0;
  double c = std::sqrt(
      factd(2*j3+1) * factd(j3+j1-j2) * factd(j3-j1+j2) * factd(j1+j2-j3) / factd(j1+j2+j3+1)
      * factd(j3+m3) * factd(j3-m3)
      / (factd(j1+m1) * factd(j1-m1) * factd(j2+m2) * factd(j2-m2)));
  double s = 0.0;
  for (int v = vmin; v <= vmax; ++v) {
    double sg = ((v + j2 + m2) & 1) ? -1.0 : 1.0;
    s += sg * factd(j2+j3+m1-v) * factd(j1-m1+v)
         / (factd(v) * factd(j3-j1+j2-v) * factd(j3+m3-v) * factd(v+j1-j2-m3));
  }
  return c * s;
}

static void qmat(int l, cd q[5][5]) {
  for (int a = 0; a < 5; ++a) for (int b = 0; b < 5; ++b) q[a][b] = cd(0, 0);
  const double s = 1.0 / std::sqrt(2.0);
  for (int m = -l; m < 0; ++m) {
    q[l + m][l - m] = cd(s, 0);
    q[l + m][l + m] = cd(0, -s);
  }
  q[l][l] = cd(1, 0);
  for (int m = 1; m <= l; ++m) {
    double sg = (m & 1) ? -1.0 : 1.0;
    q[l + m][l + m] = cd(sg * s, 0);
    q[l + m][l - m] = cd(0, sg * s);
  }
  cd ph = (l == 0) ? cd(1, 0) : (l == 1) ? cd(0, -1) : cd(-1, 0);  // (-i)^l
  for (int a = 0; a < 5; ++a) for (int b = 0; b < 5; ++b) q[a][b] *= ph;
}

static void wigner3j(int l1, int l2, int l3, double C[5][5][5]) {
  int d1 = 2*l1+1, d2 = 2*l2+1, d3 = 2*l3+1;
  cd q1[5][5], q2[5][5], q3[5][5];
  qmat(l1, q1); qmat(l2, q2); qmat(l3, q3);
  double norm2 = 0;
  for (int j = 0; j < d1; ++j)
    for (int l = 0; l < d2; ++l)
      for (int n = 0; n < d3; ++n) {
        cd sum(0, 0);
        for (int i = 0; i < d1; ++i)
          for (int k = 0; k < d2; ++k)
            for (int m = 0; m < d3; ++m) {
              double cg = su2_cg(l1, l2, l3, i - l1, k - l2, m - l3);
              if (cg != 0.0) sum += q1[i][j] * q2[k][l] * std::conj(q3[m][n]) * cg;
            }
        C[j][l][n] = sum.real();
        norm2 += C[j][l][n] * C[j][l][n];
      }
  double nrm = std::sqrt(norm2);
  if (nrm > 0)
    for (int j = 0; j < d1; ++j)
      for (int l = 0; l < d2; ++l)
        for (int n = 0; n < d3; ++n) C[j][l][n] /= nrm;
}

static void build_C_host(float C_out[NINSTR][125]) {
  const int L1[NINSTR] = {0,0,0,1,1,1,1,2,2,2,2};
  const int L2[NINSTR] = {0,1,2,0,1,1,2,0,1,2,2};
  const int L3[NINSTR] = {0,1,2,1,0,2,1,2,1,0,2};
  std::memset(C_out, 0, sizeof(float) * NINSTR * 125);
  for (int ins = 0; ins < NINSTR; ++ins) {
    int l1 = L1[ins], l2 = L2[ins], l3 = L3[ins];
    int d1 = 2*l1+1, d2 = 2*l2+1, d3 = 2*l3+1;
    double C[5][5][5];
    wigner3j(l1, l2, l3, C);
    double fan = (l3 == 0) ? 96.0 : 128.0;
    double pw = std::sqrt((2*l3+1) / fan);
    for (int i = 0; i < d1; ++i)
      for (int j = 0; j < d2; ++j)
        for (int k = 0; k < d3; ++k)
          C_out[ins][(i * d2 + j) * d3 + k] = (float)(pw * C[i][j][k]);
  }
}

extern "C" void kernel_launch(void* const* d_in, const int* in_sizes, int n_in,
                              void* d_out, int out_size, void* d_ws, size_t ws_size,
                              hipStream_t stream) {
  static float hC[NINSTR][125];
  build_C_host(hC);
  void* dC = nullptr;
  hipGetSymbolAddress(&dC, HIP_SYMBOL(g_C));
  hipMemcpyAsync(dC, hC, sizeof(hC), hipMemcpyHostToDevice, stream);

  const float* xg   = (const float*)d_in[0];
  const float* shg  = (const float*)d_in[1];
  const float* dist = (const float*)d_in[2];
  const float* freq = (const float*)d_in[3];
  const float* W1   = (const float*)d_in[4];
  const float* b1   = (const float*)d_in[5];
  const float* W2   = (const float*)d_in[6];
  const float* b2   = (const float*)d_in[7];
  float* out = (float*)d_out;
  unsigned short* W2b = (unsigned short*)d_ws;    // 720896 bytes

  prep_w2<<<(W2B_ELEMS + 255) / 256, 256, 0, stream>>>(W2, b2, W2b);

  int E = in_sizes[2];            // 16384
  int blocks = E / EPB;           // 1024
  conv_kernel<<<blocks, BLOCK, 0, stream>>>(xg, shg, dist, freq, W1, b1, W2b, out);
}

// Round 12
// 70.641 us; speedup vs baseline: 1.5514x; 1.0152x over previous
//
#include <hip/hip_runtime.h>
#include <cmath>
#include <complex>
#include <cstring>
#include <algorithm>

#define DIM_IN  288
#define DIM_SHD 9
#define NB      10
#define NH      16
#define EPB     16
#define BLOCK   256
#define NINSTR  11
#define XSTR    292
#define ZW_STRIDE 44        // per-wave z row stride (floats); 16B-aligned, 2-way banks
#define ZW_SIZE   704       // 16 * 44
#define W2B_ELEMS (NINSTR * 32 * 32 * 32)   // [ins][u][w][t0..31]; t=16 holds b2, t>16 zero

// LDS pool (floats), total 7680 fl = 30720 B -> 5 blocks/CU:
//   s_xo : [0, 4672)            16*292  x staging; reused for out gather
//   s_zw : [4672, 7488)         4 waves x 704, PRIVATE per-wave z (u-quarter)
//   s_sh : [7488, 7680)         16*12
//   s_basis: alias wave-2 z buffer (160 fl; dead before main loop, barriered)
//   s_hb   : alias wave-3 z buffer (512 ushort; dead before main loop, barriered)
#define OFF_XO 0
#define OFF_ZW 4672
#define OFF_SH 7488
#define POOLSZ 7680

typedef __attribute__((ext_vector_type(8))) short  short8b;
typedef __attribute__((ext_vector_type(4))) float  f32x4;
typedef __attribute__((ext_vector_type(2))) float  f32x2;

__device__ float g_C[NINSTR][125];

__device__ __forceinline__ unsigned short f2bf(float f) {
  unsigned int u = __float_as_uint(f);
  unsigned int r = (u + 0x7fffu + ((u >> 16) & 1u)) >> 16;   // RNE
  return (unsigned short)r;
}

// W2 -> bf16 [ins][u][w][t]; t<16 = W2 row t, t==16 = b2 (hB carries 1.0 there), t>16 = 0
__global__ __launch_bounds__(256) void prep_w2(const float* __restrict__ W2,
                                               const float* __restrict__ b2,
                                               unsigned short* __restrict__ W2b) {
  int gid = blockIdx.x * 256 + threadIdx.x;
  if (gid < W2B_ELEMS) {
    int c = gid >> 5, t = gid & 31;          // c = ins*1024 + u*32 + w
    float v = (t < 16) ? W2[(size_t)t * 11264 + c] : (t == 16 ? b2[c] : 0.0f);
    W2b[gid] = f2bf(v);
  }
}

// ---- per-WAVE z-phase: 16 edges x 8 u(quarter) = 128 tasks over 64 lanes ----
// Wave-internal producer/consumer: DS ops from one wave execute in order -> no barrier.
template<int INS,int D1,int D2,int D3,int OFF1,int OFF2>
__device__ __forceinline__ void z_phase_q(
    int lane, int q, const float* __restrict__ s_x,
    const float* __restrict__ s_sh, float* __restrict__ zw)
{
  const float* __restrict__ Cp = g_C[INS];
  constexpr int NP = D3 / 2;              // D3 odd: 1,3,5 -> 0,1,2 pairs
  #pragma unroll
  for (int s = 0; s < 2; ++s) {
    int id = lane + s * 64;
    int e = id >> 3, ul = id & 7;
    const float* xe = s_x + e * XSTR + OFF1 + (q * 8 + ul) * D1;
    f32x2 zk2[NP > 0 ? NP : 1];
    float zkl = 0.f;
    #pragma unroll
    for (int m = 0; m < NP; ++m) zk2[m] = (f32x2){0.f, 0.f};
    #pragma unroll
    for (int i = 0; i < D1; ++i) {
      float xv = xe[i];
      #pragma unroll
      for (int j = 0; j < D2; ++j) {
        float pr = xv * s_sh[e * 12 + OFF2 + j];
        f32x2 pr2 = {pr, pr};
        const float* cb = Cp + (i * D2 + j) * D3;
        #pragma unroll
        for (int m = 0; m < NP; ++m) {
          f32x2 cc = {cb[2 * m], cb[2 * m + 1]};
          zk2[m] = __builtin_elementwise_fma(cc, pr2, zk2[m]);
        }
        zkl = fmaf(cb[D3 - 1], pr, zkl);
      }
    }
    float* zo = zw + e * ZW_STRIDE + ul;
    #pragma unroll
    for (int m = 0; m < NP; ++m) {
      zo[(2 * m) * 8]     = zk2[m].x;
      zo[(2 * m + 1) * 8] = zk2[m].y;
    }
    zo[(D3 - 1) * 8] = zkl;
  }
}

// ---- MFMA weight-gen (bias folded via t=16) + pk-fma u-contraction ----
// wave = u-quarter q; per u: 2 MFMAs (w-tiles 0,1); acc = 8w x 9 packed pairs.
template<int INS,int D3,int SB>
__device__ __forceinline__ void contract_q(
    int ls, int lq, int q,
    const unsigned short* __restrict__ W2b,
    const float* __restrict__ zw, short8b hB, f32x2 (&acc)[2][2][9])
{
  const unsigned short* Ap =
      W2b + ((size_t)(INS * 32 + q * 8) * 32 + ls) * 32 + lq * 8;
  // offsets: ul*1024 (u row), wt*512 (w-tile)
  const float* zb = zw + ls * ZW_STRIDE;
  const f32x4 zero4 = {0.f, 0.f, 0.f, 0.f};

  short8b R0c = *(const short8b*)(Ap);
  short8b R1c = *(const short8b*)(Ap + 512);
  short8b R0n = *(const short8b*)(Ap + 1024);
  short8b R1n = *(const short8b*)(Ap + 1536);
  f32x4 w0_cur = __builtin_amdgcn_mfma_f32_16x16x32_bf16(R0c, hB, zero4, 0, 0, 0);
  f32x4 w1_cur = __builtin_amdgcn_mfma_f32_16x16x32_bf16(R1c, hB, zero4, 0, 0, 0);

  #pragma unroll
  for (int c = 0; c < 2; ++c) {
    float4 zq[D3];
    #pragma unroll
    for (int k = 0; k < D3; ++k)
      zq[k] = *(const float4*)(zb + k * 8 + c * 4);    // 2-way banks, free
    #pragma unroll
    for (int i = 0; i < 4; ++i) {
      const int g = c * 4 + i;              // ul (0..7)
      f32x4 w0n, w1n;
      if (g < 7) {
        w0n = __builtin_amdgcn_mfma_f32_16x16x32_bf16(R0n, hB, zero4, 0, 0, 0);
        w1n = __builtin_amdgcn_mfma_f32_16x16x32_bf16(R1n, hB, zero4, 0, 0, 0);
        if (g + 2 < 8) {
          R0n = *(const short8b*)(Ap + (size_t)(g + 2) * 1024);
          R1n = *(const short8b*)(Ap + (size_t)(g + 2) * 1024 + 512);
        }
      }
      f32x2 w0lo = {w0_cur[0], w0_cur[1]};
      f32x2 w0hi = {w0_cur[2], w0_cur[3]};
      f32x2 w1lo = {w1_cur[0], w1_cur[1]};
      f32x2 w1hi = {w1_cur[2], w1_cur[3]};
      #pragma unroll
      for (int k = 0; k < D3; ++k) {
        const float zz = (i == 0) ? zq[k].x : (i == 1) ? zq[k].y
                       : (i == 2) ? zq[k].z : zq[k].w;
        f32x2 zv = {zz, zz};
        acc[0][0][SB + k] = __builtin_elementwise_fma(w0lo, zv, acc[0][0][SB + k]);
        acc[0][1][SB + k] = __builtin_elementwise_fma(w0hi, zv, acc[0][1][SB + k]);
        acc[1][0][SB + k] = __builtin_elementwise_fma(w1lo, zv, acc[1][0][SB + k]);
        acc[1][1][SB + k] = __builtin_elementwise_fma(w1hi, zv, acc[1][1][SB + k]);
      }
      if (g < 7) { w0_cur = w0n; w1_cur = w1n; }
    }
  }
}

// NOTE (journal): VGPR cap = 256 / (2nd launch_bounds arg) on this hipcc:
// arg=2 -> 128 (r4/5/7/8/11), arg=4 -> 64 (r3/6 spill), arg=1 -> 256 (r10, TLP loss).
// r11: pk-fma halved issue count AND dropped VGPR 128->60 (71.7us).
// r12: wave=u-quarter makes z wave-private WITHOUT r9's duplication -> 0 main barriers.
__global__ __launch_bounds__(BLOCK, 2) void conv_kernel(
    const float* __restrict__ xg, const float* __restrict__ shg,
    const float* __restrict__ dist, const float* __restrict__ freq,
    const float* __restrict__ W1, const float* __restrict__ b1,
    const unsigned short* __restrict__ W2b,
    float* __restrict__ out)
{
  __shared__ float s_pool[POOLSZ];        // 30720 B -> 5 blocks/CU
  float* s_xo = s_pool + OFF_XO;
  float* s_sh = s_pool + OFF_SH;

  const int tid = threadIdx.x;
  const int e0 = blockIdx.x * EPB;
  const int lane = tid & 63;
  const int ls = lane & 15;       // e-col (B/C cols) & w-row selector (A rows)
  const int lq = lane >> 4;       // 0..3 k-slice / output reg quad
  const int q   = tid >> 6;       // 0..3 u-quarter (wave id)
  float* zw = s_pool + OFF_ZW + q * ZW_SIZE;                       // private z
  float* s_basis = s_pool + OFF_ZW + 2 * ZW_SIZE;                  // alias w2
  unsigned short* s_hb = (unsigned short*)(s_pool + OFF_ZW + 3 * ZW_SIZE); // alias w3

  // ---- prologue A: stage x (coalesced), sh, radial basis ----
  for (int i4 = tid; i4 < EPB * 72; i4 += BLOCK) {
    int e = i4 / 72, r = i4 - e * 72;
    *(float4*)(s_xo + e * XSTR + r * 4) =
        *(const float4*)(xg + (size_t)(e0 + e) * DIM_IN + r * 4);
  }
  if (tid < EPB * DIM_SHD) {
    int e = tid / DIM_SHD, c = tid - (tid / DIM_SHD) * DIM_SHD;
    s_sh[e * 12 + c] = shg[(size_t)(e0 + e) * DIM_SHD + c];
  }
  if (tid < EPB * NB) {
    int e = tid / NB, n = tid - (tid / NB) * NB;
    float d  = dist[e0 + e];
    float xv = d * 0.25f;
    float x2 = xv * xv, x4 = x2 * x2, x5 = x4 * xv;
    float env = 1.0f / xv + x5 * fmaf(xv, fmaf(xv, -21.0f, 48.0f), -28.0f);
    env = (xv < 1.0f) ? env : 0.0f;
    s_basis[e * NB + n] = env * sinf(freq[n] * xv);
  }
  __syncthreads();

  // ---- prologue B: radial MLP hidden layer (256 tasks) ----
  {
    int e = tid >> 4, t = tid & 15;
    float v = b1[t];
    #pragma unroll
    for (int n = 0; n < NB; ++n) v = fmaf(s_basis[e * NB + n], W1[n * NH + t], v);
    v = v / (1.0f + expf(-v));          // silu
    s_hb[e * 32 + t] = f2bf(v);
    s_hb[e * 32 + t + 16] = (t == 0) ? (unsigned short)0x3F80 : (unsigned short)0;
  }
  __syncthreads();
  short8b hB = *(const short8b*)(s_hb + ls * 32 + lq * 8);
  __syncthreads();   // all waves hold hB before waves 2/3 overwrite aliased buffers

  f32x2 acc[2][2][9];
  #pragma unroll
  for (int wt = 0; wt < 2; ++wt)
    #pragma unroll
    for (int p = 0; p < 2; ++p)
      #pragma unroll
      for (int a = 0; a < 9; ++a) acc[wt][p][a] = (f32x2){0.f, 0.f};

  // ---- main loop: fully wave-independent, ZERO barriers ----
  z_phase_q< 0, 1, 1, 1,   0, 0>(lane, q, s_xo, s_sh, zw);
  contract_q< 0, 1, 0>(ls, lq, q, W2b, zw, hB, acc);
  z_phase_q< 1, 1, 3, 3,   0, 1>(lane, q, s_xo, s_sh, zw);
  contract_q< 1, 3, 1>(ls, lq, q, W2b, zw, hB, acc);
  z_phase_q< 2, 1, 5, 5,   0, 4>(lane, q, s_xo, s_sh, zw);
  contract_q< 2, 5, 4>(ls, lq, q, W2b, zw, hB, acc);
  z_phase_q< 3, 3, 1, 3,  32, 0>(lane, q, s_xo, s_sh, zw);
  contract_q< 3, 3, 1>(ls, lq, q, W2b, zw, hB, acc);
  z_phase_q< 4, 3, 3, 1,  32, 1>(lane, q, s_xo, s_sh, zw);
  contract_q< 4, 1, 0>(ls, lq, q, W2b, zw, hB, acc);
  z_phase_q< 5, 3, 3, 5,  32, 1>(lane, q, s_xo, s_sh, zw);
  contract_q< 5, 5, 4>(ls, lq, q, W2b, zw, hB, acc);
  z_phase_q< 6, 3, 5, 3,  32, 4>(lane, q, s_xo, s_sh, zw);
  contract_q< 6, 3, 1>(ls, lq, q, W2b, zw, hB, acc);
  z_phase_q< 7, 5, 1, 5, 128, 0>(lane, q, s_xo, s_sh, zw);
  contract_q< 7, 5, 4>(ls, lq, q, W2b, zw, hB, acc);
  z_phase_q< 8, 5, 3, 3, 128, 1>(lane, q, s_xo, s_sh, zw);
  contract_q< 8, 3, 1>(ls, lq, q, W2b, zw, hB, acc);
  z_phase_q< 9, 5, 5, 1, 128, 4>(lane, q, s_xo, s_sh, zw);
  contract_q< 9, 1, 0>(ls, lq, q, W2b, zw, hB, acc);
  z_phase_q<10, 5, 5, 5, 128, 4>(lane, q, s_xo, s_sh, zw);
  contract_q<10, 5, 4>(ls, lq, q, W2b, zw, hB, acc);

  // ---- epilogue: 4-way u-quarter reduction into s_xo, coalesced store ----
  __syncthreads();   // everyone done reading s_xo (x) before overwrite
  #pragma unroll
  for (int ph = 3; ph >= 0; --ph) {
    if (q == ph) {
      float* row = s_xo + ls * XSTR;
      #pragma unroll
      for (int wt = 0; wt < 2; ++wt) {
        #pragma unroll
        for (int r = 0; r < 4; ++r) {
          const int w = wt * 16 + lq * 4 + r;
          float vals[9];
          #pragma unroll
          for (int a = 0; a < 9; ++a)
            vals[a] = (r & 1) ? acc[wt][r >> 1][a].y : acc[wt][r >> 1][a].x;
          if (ph == 3) {
            row[w] = vals[0];
            #pragma unroll
            for (int k = 0; k < 3; ++k) row[32 + w * 3 + k] = vals[1 + k];
            #pragma unroll
            for (int k = 0; k < 5; ++k) row[128 + w * 5 + k] = vals[4 + k];
          } else {
            row[w] += vals[0];
            #pragma unroll
            for (int k = 0; k < 3; ++k) row[32 + w * 3 + k] += vals[1 + k];
            #pragma unroll
            for (int k = 0; k < 5; ++k) row[128 + w * 5 + k] += vals[4 + k];
          }
        }
      }
    }
    __syncthreads();
  }
  // coalesced store: 16 rows x 288 = 1152 float4
  for (int i4 = tid; i4 < EPB * 72; i4 += BLOCK) {
    int e = i4 / 72, r = i4 - e * 72;
    float4 v = *(const float4*)(s_xo + e * XSTR + r * 4);
    *(float4*)(out + (size_t)(e0 + e) * DIM_IN + r * 4) = v;
  }
}

// ===================== host-side Wigner-3j (mirrors reference) =====================
typedef std::complex<double> cd;

static double factd(int n) { double r = 1; for (int i = 2; i <= n; ++i) r *= i; return r; }

static double su2_cg(int j1, int j2, int j3, int m1, int m2, int m3) {
  if (m3 != m1 + m2) return 0.0;
  int vmin = std::max(std::max(-j1 + j2 + m3, -j1 + m1), 0);
  int vmax = std::min(std::min(j2 + j3 + m1, j3 - j1 + j2), j3 + m3);
  if (vmax < vmin) return 0.0;
  double c = std::sqrt(
      factd(2*j3+1) * factd(j3+j1-j2) * factd(j3-j1+j2) * factd(j1+j2-j3) / factd(j1+j2+j3+1)
      * factd(j3+m3) * factd(j3-m3)
      / (factd(j1+m1) * factd(j1-m1) * factd(j2+m2) * factd(j2-m2)));
  double s = 0.0;
  for (int v = vmin; v <= vmax; ++v) {
    double sg = ((v + j2 + m2) & 1) ? -1.0 : 1.0;
    s += sg * factd(j2+j3+m1-v) * factd(j1-m1+v)
         / (factd(v) * factd(j3-j1+j2-v) * factd(j3+m3-v) * factd(v+j1-j2-m3));
  }
  return c * s;
}

static void qmat(int l, cd q[5][5]) {
  for (int a = 0; a < 5; ++a) for (int b = 0; b < 5; ++b) q[a][b] = cd(0, 0);
  const double s = 1.0 / std::sqrt(2.0);
  for (int m = -l; m < 0; ++m) {
    q[l + m][l - m] = cd(s, 0);
    q[l + m][l + m] = cd(0, -s);
  }
  q[l][l] = cd(1, 0);
  for (int m = 1; m <= l; ++m) {
    double sg = (m & 1) ? -1.0 : 1.0;
    q[l + m][l + m] = cd(sg * s, 0);
    q[l + m][l - m] = cd(0, sg * s);
  }
  cd ph = (l == 0) ? cd(1, 0) : (l == 1) ? cd(0, -1) : cd(-1, 0);  // (-i)^l
  for (int a = 0; a < 5; ++a) for (int b = 0; b < 5; ++b) q[a][b] *= ph;
}

static void wigner3j(int l1, int l2, int l3, double C[5][5][5]) {
  int d1 = 2*l1+1, d2 = 2*l2+1, d3 = 2*l3+1;
  cd q1[5][5], q2[5][5], q3[5][5];
  qmat(l1, q1); qmat(l2, q2); qmat(l3, q3);
  double norm2 = 0;
  for (int j = 0; j < d1; ++j)
    for (int l = 0; l < d2; ++l)
      for (int n = 0; n < d3; ++n) {
        cd sum(0, 0);
        for (int i = 0; i < d1; ++i)
          for (int k = 0; k < d2; ++k)
            for (int m = 0; m < d3; ++m) {
              double cg = su2_cg(l1, l2, l3, i - l1, k - l2, m - l3);
              if (cg != 0.0) sum += q1[i][j] * q2[k][l] * std::conj(q3[m][n]) * cg;
            }
        C[j][l][n] = sum.real();
        norm2 += C[j][l][n] * C[j][l][n];
      }
  double nrm = std::sqrt(norm2);
  if (nrm > 0)
    for (int j = 0; j < d1; ++j)
      for (int l = 0; l < d2; ++l)
        for (int n = 0; n < d3; ++n) C[j][l][n] /= nrm;
}

static void build_C_host(float C_out[NINSTR][125]) {
  const int L1[NINSTR] = {0,0,0,1,1,1,1,2,2,2,2};
  const int L2[NINSTR] = {0,1,2,0,1,1,2,0,1,2,2};
  const int L3[NINSTR] = {0,1,2,1,0,2,1,2,1,0,2};
  std::memset(C_out, 0, sizeof(float) * NINSTR * 125);
  for (int ins = 0; ins < NINSTR; ++ins) {
    int l1 = L1[ins], l2 = L2[ins], l3 = L3[ins];
    int d1 = 2*l1+1, d2 = 2*l2+1, d3 = 2*l3+1;
    double C[5][5][5];
    wigner3j(l1, l2, l3, C);
    double fan = (l3 == 0) ? 96.0 : 128.0;
    double pw = std::sqrt((2*l3+1) / fan);
    for (int i = 0; i < d1; ++i)
      for (int j = 0; j < d2; ++j)
        for (int k = 0; k < d3; ++k)
          C_out[ins][(i * d2 + j) * d3 + k] = (float)(pw * C[i][j][k]);
  }
}

extern "C" void kernel_launch(void* const* d_in, const int* in_sizes, int n_in,
                              void* d_out, int out_size, void* d_ws, size_t ws_size,
                              hipStream_t stream) {
  static float hC[NINSTR][125];
  build_C_host(hC);
  void* dC = nullptr;
  hipGetSymbolAddress(&dC, HIP_SYMBOL(g_C));
  hipMemcpyAsync(dC, hC, sizeof(hC), hipMemcpyHostToDevice, stream);

  const float* xg   = (const float*)d_in[0];
  const float* shg  = (const float*)d_in[1];
  const float* dist = (const float*)d_in[2];
  const float* freq = (const float*)d_in[3];
  const float* W1   = (const float*)d_in[4];
  const float* b1   = (const float*)d_in[5];
  const float* W2   = (const float*)d_in[6];
  const float* b2   = (const float*)d_in[7];
  float* out = (float*)d_out;
  unsigned short* W2b = (unsigned short*)d_ws;    // 720896 bytes

  prep_w2<<<(W2B_ELEMS + 255) / 256, 256, 0, stream>>>(W2, b2, W2b);

  int E = in_sizes[2];            // 16384
  int blocks = E / EPB;           // 1024
  conv_kernel<<<blocks, BLOCK, 0, stream>>>(xg, shg, dist, freq, W1, b1, W2b, out);
}

// Round 13
// 68.208 us; speedup vs baseline: 1.6067x; 1.0357x over previous
//
#include <hip/hip_runtime.h>
#include <cmath>
#include <complex>
#include <cstring>
#include <algorithm>

#define DIM_IN  288
#define DIM_SHD 9
#define NB      10
#define NH      16
#define EPB     16
#define BLOCK   256
#define NINSTR  11
#define XSTR    292
#define ZG_STRIDE 116       // per-wave z row stride (floats): 14 slots x 8u + pad, 16B-aligned
#define ZG_SIZE  (16 * ZG_STRIDE)   // 1856 fl per wave
#define W2B_ELEMS (NINSTR * 32 * 32 * 32)   // [ins][u][w][t0..31]; t=16 holds b2, t>16 zero

// LDS pool (floats), total 7616 fl = 30464 B -> 5 blocks/CU:
//   s_zw : [0, 7424)   4 waves x 1856, PRIVATE per-wave group-z
//   s_sh : [7424, 7616)
//   s_basis: alias wave-2 z (160 fl; dead before main loop, barrier-protected)
//   s_hb   : alias wave-3 z (512 ushort; dead before main loop, barrier-protected)
//   out-gather: alias s_zw[0..4672) (all z dead, barrier-protected), stride 292
#define OFF_SH 7424
#define POOLSZ 7616

typedef __attribute__((ext_vector_type(8))) short  short8b;
typedef __attribute__((ext_vector_type(4))) float  f32x4;
typedef __attribute__((ext_vector_type(2))) float  f32x2;

__device__ float g_C[NINSTR][125];

__device__ __forceinline__ unsigned short f2bf(float f) {
  unsigned int u = __float_as_uint(f);
  unsigned int r = (u + 0x7fffu + ((u >> 16) & 1u)) >> 16;   // RNE
  return (unsigned short)r;
}

// W2 -> bf16 [ins][u][w][t]; t<16 = W2 row t, t==16 = b2 (hB carries 1.0 there), t>16 = 0
__global__ __launch_bounds__(256) void prep_w2(const float* __restrict__ W2,
                                               const float* __restrict__ b2,
                                               unsigned short* __restrict__ W2b) {
  int gid = blockIdx.x * 256 + threadIdx.x;
  if (gid < W2B_ELEMS) {
    int c = gid >> 5, t = gid & 31;          // c = ins*1024 + u*32 + w
    float v = (t < 16) ? W2[(size_t)t * 11264 + c] : (t == 16 ? b2[c] : 0.0f);
    W2b[gid] = f2bf(v);
  }
}

// ---- one instruction's z from in-register x, pk-fma packed ----
template<int INS,int D1,int D2,int D3,int OFF2,int SLOT>
__device__ __forceinline__ void z_one(const float (&xv)[D1],
                                      const float* __restrict__ she,
                                      float* __restrict__ zo)
{
  const float* __restrict__ Cp = g_C[INS];
  constexpr int NP = D3 / 2;              // D3 odd: 1,3,5 -> 0,1,2 pairs
  f32x2 zk2[NP > 0 ? NP : 1];
  float zkl = 0.f;
  #pragma unroll
  for (int m = 0; m < NP; ++m) zk2[m] = (f32x2){0.f, 0.f};
  #pragma unroll
  for (int i = 0; i < D1; ++i) {
    #pragma unroll
    for (int j = 0; j < D2; ++j) {
      float pr = xv[i] * she[OFF2 + j];
      f32x2 pr2 = {pr, pr};
      const float* cb = Cp + (i * D2 + j) * D3;
      #pragma unroll
      for (int m = 0; m < NP; ++m) {
        f32x2 cc = {cb[2 * m], cb[2 * m + 1]};
        zk2[m] = __builtin_elementwise_fma(cc, pr2, zk2[m]);
      }
      zkl = fmaf(cb[D3 - 1], pr, zkl);
    }
  }
  #pragma unroll
  for (int m = 0; m < NP; ++m) {
    zo[(SLOT + 2 * m) * 8]     = zk2[m].x;
    zo[(SLOT + 2 * m + 1) * 8] = zk2[m].y;
  }
  zo[(SLOT + D3 - 1) * 8] = zkl;
}

// ---- per-WAVE group z-phases: 16e x 8u tasks over 64 lanes, x from GLOBAL ----
template<int D1,int OFF1>
__device__ __forceinline__ void load_x(const float* __restrict__ xg, int e0,
                                       int e, int u, float (&xv)[D1]) {
  const float* xp = xg + (size_t)(e0 + e) * DIM_IN + OFF1 + u * D1;
  #pragma unroll
  for (int i = 0; i < D1; ++i) xv[i] = xp[i];
}

__device__ __forceinline__ void z_group_l0(int lane, int q, int e0,
    const float* __restrict__ xg, const float* __restrict__ s_sh,
    float* __restrict__ zw) {
  #pragma unroll
  for (int s = 0; s < 2; ++s) {
    int id = lane + s * 64;
    int e = id >> 3, ul = id & 7, u = q * 8 + ul;
    float xv[1];
    load_x<1, 0>(xg, e0, e, u, xv);
    const float* she = s_sh + e * 12;
    float* zo = zw + e * ZG_STRIDE + ul;
    z_one<0, 1, 1, 1, 0, 0>(xv, she, zo);
    z_one<1, 1, 3, 3, 1, 1>(xv, she, zo);
    z_one<2, 1, 5, 5, 4, 4>(xv, she, zo);
  }
}

__device__ __forceinline__ void z_group_l1(int lane, int q, int e0,
    const float* __restrict__ xg, const float* __restrict__ s_sh,
    float* __restrict__ zw) {
  #pragma unroll
  for (int s = 0; s < 2; ++s) {
    int id = lane + s * 64;
    int e = id >> 3, ul = id & 7, u = q * 8 + ul;
    float xv[3];
    load_x<3, 32>(xg, e0, e, u, xv);
    const float* she = s_sh + e * 12;
    float* zo = zw + e * ZG_STRIDE + ul;
    z_one<3, 3, 1, 3, 0, 0>(xv, she, zo);
    z_one<4, 3, 3, 1, 1, 3>(xv, she, zo);
    z_one<5, 3, 3, 5, 1, 4>(xv, she, zo);
    z_one<6, 3, 5, 3, 4, 9>(xv, she, zo);
  }
}

__device__ __forceinline__ void z_group_l2(int lane, int q, int e0,
    const float* __restrict__ xg, const float* __restrict__ s_sh,
    float* __restrict__ zw) {
  #pragma unroll
  for (int s = 0; s < 2; ++s) {
    int id = lane + s * 64;
    int e = id >> 3, ul = id & 7, u = q * 8 + ul;
    float xv[5];
    load_x<5, 128>(xg, e0, e, u, xv);
    const float* she = s_sh + e * 12;
    float* zo = zw + e * ZG_STRIDE + ul;
    z_one< 7, 5, 1, 5, 0, 0>(xv, she, zo);
    z_one< 8, 5, 3, 3, 1, 5>(xv, she, zo);
    z_one< 9, 5, 5, 1, 4, 8>(xv, she, zo);
    z_one<10, 5, 5, 5, 4, 9>(xv, she, zo);
  }
}

// ---- MFMA weight-gen (bias folded via t=16) + pk-fma u-contraction ----
// wave = u-quarter q; per u: 2 MFMAs (w-tiles 0,1); acc = 8w x 9 packed pairs.
template<int INS,int D3,int SB,int SLOT>
__device__ __forceinline__ void contract_q(
    int ls, int lq, int q,
    const unsigned short* __restrict__ W2b,
    const float* __restrict__ zw, short8b hB, f32x2 (&acc)[2][2][9])
{
  const unsigned short* Ap =
      W2b + ((size_t)(INS * 32 + q * 8) * 32 + ls) * 32 + lq * 8;
  // offsets: ul*1024 (u row), wt*512 (w-tile)
  const float* zb = zw + ls * ZG_STRIDE + SLOT * 8;
  const f32x4 zero4 = {0.f, 0.f, 0.f, 0.f};

  short8b R0c = *(const short8b*)(Ap);
  short8b R1c = *(const short8b*)(Ap + 512);
  short8b R0n = *(const short8b*)(Ap + 1024);
  short8b R1n = *(const short8b*)(Ap + 1536);
  f32x4 w0_cur = __builtin_amdgcn_mfma_f32_16x16x32_bf16(R0c, hB, zero4, 0, 0, 0);
  f32x4 w1_cur = __builtin_amdgcn_mfma_f32_16x16x32_bf16(R1c, hB, zero4, 0, 0, 0);

  #pragma unroll
  for (int c = 0; c < 2; ++c) {
    float4 zq[D3];
    #pragma unroll
    for (int k = 0; k < D3; ++k)
      zq[k] = *(const float4*)(zb + k * 8 + c * 4);    // 2-way banks, free
    #pragma unroll
    for (int i = 0; i < 4; ++i) {
      const int g = c * 4 + i;              // ul (0..7)
      f32x4 w0n, w1n;
      if (g < 7) {
        w0n = __builtin_amdgcn_mfma_f32_16x16x32_bf16(R0n, hB, zero4, 0, 0, 0);
        w1n = __builtin_amdgcn_mfma_f32_16x16x32_bf16(R1n, hB, zero4, 0, 0, 0);
        if (g + 2 < 8) {
          R0n = *(const short8b*)(Ap + (size_t)(g + 2) * 1024);
          R1n = *(const short8b*)(Ap + (size_t)(g + 2) * 1024 + 512);
        }
      }
      f32x2 w0lo = {w0_cur[0], w0_cur[1]};
      f32x2 w0hi = {w0_cur[2], w0_cur[3]};
      f32x2 w1lo = {w1_cur[0], w1_cur[1]};
      f32x2 w1hi = {w1_cur[2], w1_cur[3]};
      #pragma unroll
      for (int k = 0; k < D3; ++k) {
        const float zz = (i == 0) ? zq[k].x : (i == 1) ? zq[k].y
                       : (i == 2) ? zq[k].z : zq[k].w;
        f32x2 zv = {zz, zz};
        acc[0][0][SB + k] = __builtin_elementwise_fma(w0lo, zv, acc[0][0][SB + k]);
        acc[0][1][SB + k] = __builtin_elementwise_fma(w0hi, zv, acc[0][1][SB + k]);
        acc[1][0][SB + k] = __builtin_elementwise_fma(w1lo, zv, acc[1][0][SB + k]);
        acc[1][1][SB + k] = __builtin_elementwise_fma(w1hi, zv, acc[1][1][SB + k]);
      }
      if (g < 7) { w0_cur = w0n; w1_cur = w1n; }
    }
  }
}

// NOTE (journal): VGPR cap = 256 / (2nd launch_bounds arg) on this hipcc:
// arg=2 -> 128 (r4/5/7/8/11/12), arg=4 -> 64 (r3/6 spill), arg=1 -> 256 (r10, TLP loss).
// r11 pk-fma: 71.7us, VGPR 60. r12 zero-barrier u-quarter: 70.6us (conflicts up).
// r13: group-fused z (3 calls) -> 3-4 back-to-back contracts, deep A-load overlap;
//      x read from global per group (L2-resident, read-once), s_xo deleted.
__global__ __launch_bounds__(BLOCK, 2) void conv_kernel(
    const float* __restrict__ xg, const float* __restrict__ shg,
    const float* __restrict__ dist, const float* __restrict__ freq,
    const float* __restrict__ W1, const float* __restrict__ b1,
    const unsigned short* __restrict__ W2b,
    float* __restrict__ out)
{
  __shared__ float s_pool[POOLSZ];        // 30464 B -> 5 blocks/CU
  float* s_sh = s_pool + OFF_SH;

  const int tid = threadIdx.x;
  const int e0 = blockIdx.x * EPB;
  const int lane = tid & 63;
  const int ls = lane & 15;       // e-col (B/C cols) & w-row selector (A rows)
  const int lq = lane >> 4;       // 0..3 k-slice / output reg quad
  const int q   = tid >> 6;       // 0..3 u-quarter (wave id)
  float* zw = s_pool + q * ZG_SIZE;                        // private group-z
  float* s_basis = s_pool + 2 * ZG_SIZE;                   // alias wave-2 z
  unsigned short* s_hb = (unsigned short*)(s_pool + 3 * ZG_SIZE); // alias wave-3 z

  // ---- prologue A: sh + radial basis ----
  if (tid < EPB * DIM_SHD) {
    int e = tid / DIM_SHD, c = tid - (tid / DIM_SHD) * DIM_SHD;
    s_sh[e * 12 + c] = shg[(size_t)(e0 + e) * DIM_SHD + c];
  }
  if (tid < EPB * NB) {
    int e = tid / NB, n = tid - (tid / NB) * NB;
    float d  = dist[e0 + e];
    float xv = d * 0.25f;
    float x2 = xv * xv, x4 = x2 * x2, x5 = x4 * xv;
    float env = 1.0f / xv + x5 * fmaf(xv, fmaf(xv, -21.0f, 48.0f), -28.0f);
    env = (xv < 1.0f) ? env : 0.0f;
    s_basis[e * NB + n] = env * sinf(freq[n] * xv);
  }
  __syncthreads();

  // ---- prologue B: radial MLP hidden layer (256 tasks) ----
  {
    int e = tid >> 4, t = tid & 15;
    float v = b1[t];
    #pragma unroll
    for (int n = 0; n < NB; ++n) v = fmaf(s_basis[e * NB + n], W1[n * NH + t], v);
    v = v / (1.0f + expf(-v));          // silu
    s_hb[e * 32 + t] = f2bf(v);
    s_hb[e * 32 + t + 16] = (t == 0) ? (unsigned short)0x3F80 : (unsigned short)0;
  }
  __syncthreads();
  short8b hB = *(const short8b*)(s_hb + ls * 32 + lq * 8);
  __syncthreads();   // all waves hold hB before waves 2/3 overwrite aliased buffers

  f32x2 acc[2][2][9];
  #pragma unroll
  for (int wt = 0; wt < 2; ++wt)
    #pragma unroll
    for (int p = 0; p < 2; ++p)
      #pragma unroll
      for (int a = 0; a < 9; ++a) acc[wt][p][a] = (f32x2){0.f, 0.f};

  // ---- main loop: wave-independent, zero barriers, grouped ----
  z_group_l0(lane, q, e0, xg, s_sh, zw);
  contract_q< 0, 1, 0, 0>(ls, lq, q, W2b, zw, hB, acc);
  contract_q< 1, 3, 1, 1>(ls, lq, q, W2b, zw, hB, acc);
  contract_q< 2, 5, 4, 4>(ls, lq, q, W2b, zw, hB, acc);

  z_group_l1(lane, q, e0, xg, s_sh, zw);
  contract_q< 3, 3, 1, 0>(ls, lq, q, W2b, zw, hB, acc);
  contract_q< 4, 1, 0, 3>(ls, lq, q, W2b, zw, hB, acc);
  contract_q< 5, 5, 4, 4>(ls, lq, q, W2b, zw, hB, acc);
  contract_q< 6, 3, 1, 9>(ls, lq, q, W2b, zw, hB, acc);

  z_group_l2(lane, q, e0, xg, s_sh, zw);
  contract_q< 7, 5, 4, 0>(ls, lq, q, W2b, zw, hB, acc);
  contract_q< 8, 3, 1, 5>(ls, lq, q, W2b, zw, hB, acc);
  contract_q< 9, 1, 0, 8>(ls, lq, q, W2b, zw, hB, acc);
  contract_q<10, 5, 4, 9>(ls, lq, q, W2b, zw, hB, acc);

  // ---- epilogue: 4-way u-quarter reduction into pool (z dead), store ----
  __syncthreads();
  float* s_og = s_pool;            // stride XSTR=292, 4672 fl <= z region
  #pragma unroll
  for (int ph = 3; ph >= 0; --ph) {
    if (q == ph) {
      float* row = s_og + ls * XSTR;
      #pragma unroll
      for (int wt = 0; wt < 2; ++wt) {
        #pragma unroll
        for (int r = 0; r < 4; ++r) {
          const int w = wt * 16 + lq * 4 + r;
          float vals[9];
          #pragma unroll
          for (int a = 0; a < 9; ++a)
            vals[a] = (r & 1) ? acc[wt][r >> 1][a].y : acc[wt][r >> 1][a].x;
          if (ph == 3) {
            row[w] = vals[0];
            #pragma unroll
            for (int k = 0; k < 3; ++k) row[32 + w * 3 + k] = vals[1 + k];
            #pragma unroll
            for (int k = 0; k < 5; ++k) row[128 + w * 5 + k] = vals[4 + k];
          } else {
            row[w] += vals[0];
            #pragma unroll
            for (int k = 0; k < 3; ++k) row[32 + w * 3 + k] += vals[1 + k];
            #pragma unroll
            for (int k = 0; k < 5; ++k) row[128 + w * 5 + k] += vals[4 + k];
          }
        }
      }
    }
    __syncthreads();
  }
  // coalesced store: 16 rows x 288 = 1152 float4
  for (int i4 = tid; i4 < EPB * 72; i4 += BLOCK) {
    int e = i4 / 72, r = i4 - e * 72;
    float4 v = *(const float4*)(s_og + e * XSTR + r * 4);
    *(float4*)(out + (size_t)(e0 + e) * DIM_IN + r * 4) = v;
  }
}

// ===================== host-side Wigner-3j (mirrors reference) =====================
typedef std::complex<double> cd;

static double factd(int n) { double r = 1; for (int i = 2; i <= n; ++i) r *= i; return r; }

static double su2_cg(int j1, int j2, int j3, int m1, int m2, int m3) {
  if (m3 != m1 + m2) return 0.0;
  int vmin = std::max(std::max(-j1 + j2 + m3, -j1 + m1), 0);
  int vmax = std::min(std::min(j2 + j3 + m1, j3 - j1 + j2), j3 + m3);
  if (vmax < vmin) return 0.0;
  double c = std::sqrt(
      factd(2*j3+1) * factd(j3+j1-j2) * factd(j3-j1+j2) * factd(j1+j2-j3) / factd(j1+j2+j3+1)
      * factd(j3+m3) * factd(j3-m3)
      / (factd(j1+m1) * factd(j1-m1) * factd(j2+m2) * factd(j2-m2)));
  double s = 0.0;
  for (int v = vmin; v <= vmax; ++v) {
    double sg = ((v + j2 + m2) & 1) ? -1.0 : 1.0;
    s += sg * factd(j2+j3+m1-v) * factd(j1-m1+v)
         / (factd(v) * factd(j3-j1+j2-v) * factd(j3+m3-v) * factd(v+j1-j2-m3));
  }
  return c * s;
}

static void qmat(int l, cd q[5][5]) {
  for (int a = 0; a < 5; ++a) for (int b = 0; b < 5; ++b) q[a][b] = cd(0, 0);
  const double s = 1.0 / std::sqrt(2.0);
  for (int m = -l; m < 0; ++m) {
    q[l + m][l - m] = cd(s, 0);
    q[l + m][l + m] = cd(0, -s);
  }
  q[l][l] = cd(1, 0);
  for (int m = 1; m <= l; ++m) {
    double sg = (m & 1) ? -1.0 : 1.0;
    q[l + m][l + m] = cd(sg * s, 0);
    q[l + m][l - m] = cd(0, sg * s);
  }
  cd ph = (l == 0) ? cd(1, 0) : (l == 1) ? cd(0, -1) : cd(-1, 0);  // (-i)^l
  for (int a = 0; a < 5; ++a) for (int b = 0; b < 5; ++b) q[a][b] *= ph;
}

static void wigner3j(int l1, int l2, int l3, double C[5][5][5]) {
  int d1 = 2*l1+1, d2 = 2*l2+1, d3 = 2*l3+1;
  cd q1[5][5], q2[5][5], q3[5][5];
  qmat(l1, q1); qmat(l2, q2); qmat(l3, q3);
  double norm2 = 0;
  for (int j = 0; j < d1; ++j)
    for (int l = 0; l < d2; ++l)
      for (int n = 0; n < d3; ++n) {
        cd sum(0, 0);
        for (int i = 0; i < d1; ++i)
          for (int k = 0; k < d2; ++k)
            for (int m = 0; m < d3; ++m) {
              double cg = su2_cg(l1, l2, l3, i - l1, k - l2, m - l3);
              if (cg != 0.0) sum += q1[i][j] * q2[k][l] * std::conj(q3[m][n]) * cg;
            }
        C[j][l][n] = sum.real();
        norm2 += C[j][l][n] * C[j][l][n];
      }
  double nrm = std::sqrt(norm2);
  if (nrm > 0)
    for (int j = 0; j < d1; ++j)
      for (int l = 0; l < d2; ++l)
        for (int n = 0; n < d3; ++n) C[j][l][n] /= nrm;
}

static void build_C_host(float C_out[NINSTR][125]) {
  const int L1[NINSTR] = {0,0,0,1,1,1,1,2,2,2,2};
  const int L2[NINSTR] = {0,1,2,0,1,1,2,0,1,2,2};
  const int L3[NINSTR] = {0,1,2,1,0,2,1,2,1,0,2};
  std::memset(C_out, 0, sizeof(float) * NINSTR * 125);
  for (int ins = 0; ins < NINSTR; ++ins) {
    int l1 = L1[ins], l2 = L2[ins], l3 = L3[ins];
    int d1 = 2*l1+1, d2 = 2*l2+1, d3 = 2*l3+1;
    double C[5][5][5];
    wigner3j(l1, l2, l3, C);
    double fan = (l3 == 0) ? 96.0 : 128.0;
    double pw = std::sqrt((2*l3+1) / fan);
    for (int i = 0; i < d1; ++i)
      for (int j = 0; j < d2; ++j)
        for (int k = 0; k < d3; ++k)
          C_out[ins][(i * d2 + j) * d3 + k] = (float)(pw * C[i][j][k]);
  }
}

extern "C" void kernel_launch(void* const* d_in, const int* in_sizes, int n_in,
                              void* d_out, int out_size, void* d_ws, size_t ws_size,
                              hipStream_t stream) {
  static float hC[NINSTR][125];
  build_C_host(hC);
  void* dC = nullptr;
  hipGetSymbolAddress(&dC, HIP_SYMBOL(g_C));
  hipMemcpyAsync(dC, hC, sizeof(hC), hipMemcpyHostToDevice, stream);

  const float* xg   = (const float*)d_in[0];
  const float* shg  = (const float*)d_in[1];
  const float* dist = (const float*)d_in[2];
  const float* freq = (const float*)d_in[3];
  const float* W1   = (const float*)d_in[4];
  const float* b1   = (const float*)d_in[5];
  const float* W2   = (const float*)d_in[6];
  const float* b2   = (const float*)d_in[7];
  float* out = (float*)d_out;
  unsigned short* W2b = (unsigned short*)d_ws;    // 720896 bytes

  prep_w2<<<(W2B_ELEMS + 255) / 256, 256, 0, stream>>>(W2, b2, W2b);

  int E = in_sizes[2];            // 16384
  int blocks = E / EPB;           // 1024
  conv_kernel<<<blocks, BLOCK, 0, stream>>>(xg, shg, dist, freq, W1, b1, W2b, out);
}